// Round 2
// baseline (321.792 us; speedup 1.0000x reference)
//
#include <hip/hip_runtime.h>
#include <hip/hip_bf16.h>

// NRI edge-MLP encoder: out[b,e,:] = relu(concat(x[b,send(e)], x[b,recv(e)]) @ W1^T + b1) @ W2^T + b2
// B=8, N=256, E=65280, n_in=64, n_hid=128, n_out=64.
// edge e: recv = e/255, k = e%255, send = k + (k >= recv)   [np.where row-major order]

using frag_t = __attribute__((ext_vector_type(8))) short;   // 8 bf16 = 4 VGPRs
using f32x4  = __attribute__((ext_vector_type(4))) float;

#define X_ELEMS  (8 * 256 * 64)   // 131072
#define W1_ELEMS (128 * 128)      // 16384
#define W2_ELEMS (64 * 128)       // 8192
#define W1_OFF   X_ELEMS
#define W2_OFF   (X_ELEMS + W1_ELEMS)

__device__ inline unsigned short f2bf(float f) {
    union { float f; unsigned u; } v; v.f = f;
    unsigned r = v.u + 0x7fffu + ((v.u >> 16) & 1u);   // RTNE
    return (unsigned short)(r >> 16);
}

__global__ __launch_bounds__(256) void cvt_bf16(const float* __restrict__ x,
                                                const float* __restrict__ W1,
                                                const float* __restrict__ W2,
                                                unsigned short* __restrict__ ws) {
    int i = blockIdx.x * 256 + threadIdx.x;
    if (i < X_ELEMS)  ws[i]          = f2bf(x[i]);
    if (i < W1_ELEMS) ws[W1_OFF + i] = f2bf(W1[i]);
    if (i < W2_ELEMS) ws[W2_OFF + i] = f2bf(W2[i]);
}

// grid = 8 batches x 255 blocks of 256 edges = 2040 blocks.
// Each wave: 64 edges = 2 jobs x (2 tiles of 16 rows). No barriers anywhere:
// H staging rows are wave-private. launch_bounds(256,4): LDS 34.8KB -> 4 blk/CU.
__global__ __launch_bounds__(256, 4) void nri_mlp(const unsigned short* __restrict__ ws,
                                                  const float* __restrict__ b1,
                                                  const float* __restrict__ b2,
                                                  float* __restrict__ out) {
    const unsigned short* xbf  = ws;
    const unsigned short* W1bf = ws + W1_OFF;
    const unsigned short* W2bf = ws + W2_OFF;

    // Per-wave 32-row H buffer, bf16, row stride 136 (pad +8 -> only 2-way
    // bank aliasing on the b128 reads, which is free).
    __shared__ unsigned short Hs[4 * 32 * 136];   // 34816 B

    const int tid  = threadIdx.x;
    const int wave = tid >> 6;
    const int lane = tid & 63;
    const int quad = lane >> 4;
    const int n16  = lane & 15;

    const int bx = blockIdx.x;
    const int b  = bx / 255;
    const int eb = (bx - b * 255) * 256;   // 256 edges per block

    const unsigned short* xb = xbf + b * (256 * 64);
    unsigned short* Hw = &Hs[wave * (32 * 136)];

    const float bv1[2] = {0.f, 0.f};  // placeholder to keep structure simple (unused)
    (void)bv1;

    #pragma unroll
    for (int j = 0; j < 2; ++j) {
        const int e0 = eb + wave * 64 + j * 32;   // first edge of this job

        // Per-lane gather pointers. A-operand layout: lane holds
        // A[m = lane&15][k = quad*8 + jj].
        const unsigned short* pa[2][2];   // [tile][0=send half, 1=recv half]
        #pragma unroll
        for (int t = 0; t < 2; ++t) {
            int e    = e0 + t * 16 + n16;
            int recv = e / 255;
            int kk   = e - recv * 255;
            int send = kk + (kk >= recv ? 1 : 0);
            pa[t][0] = xb + send * 64;
            pa[t][1] = xb + recv * 64;
        }

        // ---------- Layer 1: [32 x 128] = edges[32 x 128] @ W1^T ----------
        f32x4 acc[2][8];
        #pragma unroll
        for (int t = 0; t < 2; ++t)
            #pragma unroll
            for (int c = 0; c < 8; ++c)
                acc[t][c] = (f32x4){0.f, 0.f, 0.f, 0.f};

        #pragma unroll
        for (int ks = 0; ks < 4; ++ks) {          // K = 128 = 4 x 32
            frag_t a[2];
            #pragma unroll
            for (int t = 0; t < 2; ++t)
                a[t] = *(const frag_t*)(pa[t][ks >> 1] + (ks & 1) * 32 + quad * 8);
            #pragma unroll
            for (int c = 0; c < 8; ++c) {
                frag_t bf = *(const frag_t*)(W1bf + (c * 16 + n16) * 128 + ks * 32 + quad * 8);
                #pragma unroll
                for (int t = 0; t < 2; ++t)
                    acc[t][c] = __builtin_amdgcn_mfma_f32_16x16x32_bf16(a[t], bf, acc[t][c], 0, 0, 0);
            }
        }

        // bias + ReLU -> Hw  (C/D layout: col = lane&15, row = quad*4 + reg)
        #pragma unroll
        for (int c = 0; c < 8; ++c) {
            float bv = b1[c * 16 + n16];
            #pragma unroll
            for (int t = 0; t < 2; ++t) {
                #pragma unroll
                for (int r = 0; r < 4; ++r) {
                    float v = acc[t][c][r] + bv;
                    v = v > 0.f ? v : 0.f;
                    int row = t * 16 + quad * 4 + r;
                    Hw[row * 136 + c * 16 + n16] = f2bf(v);
                }
            }
        }
        // no barrier: Hw is wave-private; compiler orders via lgkmcnt

        // ---------- Layer 2: [32 x 64] = H[32 x 128] @ W2^T ----------
        f32x4 acc2[2][4];
        #pragma unroll
        for (int t = 0; t < 2; ++t)
            #pragma unroll
            for (int c = 0; c < 4; ++c)
                acc2[t][c] = (f32x4){0.f, 0.f, 0.f, 0.f};

        #pragma unroll
        for (int ks = 0; ks < 4; ++ks) {
            frag_t a[2];
            #pragma unroll
            for (int t = 0; t < 2; ++t)
                a[t] = *(const frag_t*)&Hw[(t * 16 + n16) * 136 + ks * 32 + quad * 8];
            #pragma unroll
            for (int c = 0; c < 4; ++c) {
                frag_t bf = *(const frag_t*)(W2bf + (c * 16 + n16) * 128 + ks * 32 + quad * 8);
                #pragma unroll
                for (int t = 0; t < 2; ++t)
                    acc2[t][c] = __builtin_amdgcn_mfma_f32_16x16x32_bf16(a[t], bf, acc2[t][c], 0, 0, 0);
            }
        }

        // Epilogue: fp32 stores (4 x 64B segments per instr)
        float* ob = out + ((long)b * 65280 + e0) * 64;
        #pragma unroll
        for (int c = 0; c < 4; ++c) {
            float bv = b2[c * 16 + n16];
            #pragma unroll
            for (int t = 0; t < 2; ++t) {
                #pragma unroll
                for (int r = 0; r < 4; ++r) {
                    int row = t * 16 + quad * 4 + r;
                    ob[row * 64 + c * 16 + n16] = acc2[t][c][r] + bv;
                }
            }
        }
    }
}

extern "C" void kernel_launch(void* const* d_in, const int* in_sizes, int n_in,
                              void* d_out, int out_size, void* d_ws, size_t ws_size,
                              hipStream_t stream) {
    const float* x  = (const float*)d_in[0];
    // d_in[1] = rel_rec, d_in[2] = rel_send: one-hot incidence, replaced by index math
    const float* W1 = (const float*)d_in[3];
    const float* b1 = (const float*)d_in[4];
    const float* W2 = (const float*)d_in[5];
    const float* b2 = (const float*)d_in[6];
    unsigned short* ws = (unsigned short*)d_ws;
    float* out = (float*)d_out;

    cvt_bf16<<<512, 256, 0, stream>>>(x, W1, W2, ws);
    // 8 batches x 255 edge-blocks of 256 edges
    nri_mlp<<<2040, 256, 0, stream>>>(ws, b1, b2, out);
}

// Round 3
// 307.136 us; speedup vs baseline: 1.0477x; 1.0477x over previous
//
#include <hip/hip_runtime.h>
#include <hip/hip_bf16.h>

// NRI edge-MLP encoder: out[b,e,:] = relu(concat(x[b,send(e)], x[b,recv(e)]) @ W1^T + b1) @ W2^T + b2
// B=8, N=256, E=65280, n_in=64, n_hid=128, n_out=64.
// edge e: recv = e/255, k = e%255, send = k + (k >= recv)   [np.where row-major order]

using frag_t  = __attribute__((ext_vector_type(8))) short;          // 8 bf16 = 4 VGPRs
using f32x4   = __attribute__((ext_vector_type(4))) float;
using ushort8 = __attribute__((ext_vector_type(8))) unsigned short;

#define X_ELEMS  (8 * 256 * 64)   // 131072
#define W1_ELEMS (128 * 128)      // 16384
#define W2_ELEMS (64 * 128)       // 8192
#define W1_OFF   X_ELEMS
#define W2_OFF   (X_ELEMS + W1_ELEMS)

__device__ inline unsigned short f2bf(float f) {
    union { float f; unsigned u; } v; v.f = f;
    unsigned r = v.u + 0x7fffu + ((v.u >> 16) & 1u);   // RTNE
    return (unsigned short)(r >> 16);
}

__device__ inline void cvt8(const float* __restrict__ s, unsigned short* __restrict__ d) {
    f32x4 a = *(const f32x4*)s;
    f32x4 b = *(const f32x4*)(s + 4);
    ushort8 o;
    o[0] = f2bf(a[0]); o[1] = f2bf(a[1]); o[2] = f2bf(a[2]); o[3] = f2bf(a[3]);
    o[4] = f2bf(b[0]); o[5] = f2bf(b[1]); o[6] = f2bf(b[2]); o[7] = f2bf(b[3]);
    *(ushort8*)d = o;
}

__global__ __launch_bounds__(256) void cvt_bf16(const float* __restrict__ x,
                                                const float* __restrict__ W1,
                                                const float* __restrict__ W2,
                                                unsigned short* __restrict__ ws) {
    int g = blockIdx.x * 256 + threadIdx.x;           // 64 blocks -> 16384 threads
    cvt8(x + g * 8, ws + g * 8);                      // 16384*8 = X_ELEMS exactly
    if (g < W1_ELEMS / 8) cvt8(W1 + g * 8, ws + W1_OFF + g * 8);
    if (g < W2_ELEMS / 8) cvt8(W2 + g * 8, ws + W2_OFF + g * 8);
}

// grid = 4080: b = bx & 7 (XCD-pinned batch), eb = (bx>>3)*128 edges.
// Each wave owns 32 edges (2 MFMA row-tiles), one job, no barriers (H wave-private).
// LDS 34816 B -> 4 blocks/CU; launch_bounds(256,4) caps VGPR at 128 (16 waves/CU).
__global__ __launch_bounds__(256, 4) void nri_mlp(const unsigned short* __restrict__ ws,
                                                  const float* __restrict__ b1,
                                                  const float* __restrict__ b2,
                                                  float* __restrict__ out) {
    const unsigned short* xbf  = ws;
    const unsigned short* W1bf = ws + W1_OFF;
    const unsigned short* W2bf = ws + W2_OFF;

    // Per-wave 8704 B region. Phase 1: H as bf16 [32 rows x 136] (pad -> b128
    // reads are 2-way aliased = free). Phase 2 (epilogue): reused as fp32
    // [32 rows x 68] staging for coalesced output stores.
    __shared__ unsigned short Hs[4 * 32 * 136];   // 34816 B

    const int tid  = threadIdx.x;
    const int wave = tid >> 6;
    const int lane = tid & 63;
    const int quad = lane >> 4;
    const int n16  = lane & 15;

    const int bx = blockIdx.x;
    const int b  = bx & 7;                 // XCD-pinned batch
    const int eb = (bx >> 3) * 128;        // 128 edges per block
    const int e0 = eb + wave * 32;         // this wave's 32 edges

    const unsigned short* xb = xbf + b * (256 * 64);
    unsigned short* Hw = &Hs[wave * (32 * 136)];

    // Per-lane gather pointers. A-operand layout: lane holds A[m=lane&15][k=quad*8+j].
    const unsigned short* pa[2][2];   // [tile][0=send half, 1=recv half]
    #pragma unroll
    for (int t = 0; t < 2; ++t) {
        int e    = e0 + t * 16 + n16;
        int recv = e / 255;
        int kk   = e - recv * 255;
        int send = kk + (kk >= recv ? 1 : 0);
        pa[t][0] = xb + send * 64;
        pa[t][1] = xb + recv * 64;
    }

    // ---------- Layer 1: [32 x 128] = edges[32 x 128] @ W1^T ----------
    f32x4 acc[2][8];
    #pragma unroll
    for (int t = 0; t < 2; ++t)
        #pragma unroll
        for (int c = 0; c < 8; ++c)
            acc[t][c] = (f32x4){0.f, 0.f, 0.f, 0.f};

    #pragma unroll
    for (int ks = 0; ks < 4; ++ks) {          // K = 128 = 4 x 32
        frag_t a[2];
        #pragma unroll
        for (int t = 0; t < 2; ++t)
            a[t] = *(const frag_t*)(pa[t][ks >> 1] + (ks & 1) * 32 + quad * 8);
        #pragma unroll
        for (int c = 0; c < 8; ++c) {
            frag_t bf = *(const frag_t*)(W1bf + (c * 16 + n16) * 128 + ks * 32 + quad * 8);
            #pragma unroll
            for (int t = 0; t < 2; ++t)
                acc[t][c] = __builtin_amdgcn_mfma_f32_16x16x32_bf16(a[t], bf, acc[t][c], 0, 0, 0);
        }
    }

    // bias + ReLU -> Hw bf16 (C/D layout: col = lane&15, row = quad*4 + reg)
    #pragma unroll
    for (int c = 0; c < 8; ++c) {
        float bv = b1[c * 16 + n16];
        #pragma unroll
        for (int t = 0; t < 2; ++t) {
            #pragma unroll
            for (int r = 0; r < 4; ++r) {
                float v = acc[t][c][r] + bv;
                v = v > 0.f ? v : 0.f;
                int row = t * 16 + quad * 4 + r;
                Hw[row * 136 + c * 16 + n16] = f2bf(v);
            }
        }
    }
    // no barrier: Hw is wave-private; in-wave LDS ordering via lgkmcnt

    // ---------- Layer 2: [32 x 64] = H[32 x 128] @ W2^T ----------
    f32x4 acc2[2][4];
    #pragma unroll
    for (int t = 0; t < 2; ++t)
        #pragma unroll
        for (int c = 0; c < 4; ++c)
            acc2[t][c] = (f32x4){0.f, 0.f, 0.f, 0.f};

    #pragma unroll
    for (int ks = 0; ks < 4; ++ks) {
        frag_t a[2];
        #pragma unroll
        for (int t = 0; t < 2; ++t)
            a[t] = *(const frag_t*)&Hw[(t * 16 + n16) * 136 + ks * 32 + quad * 8];
        #pragma unroll
        for (int c = 0; c < 4; ++c) {
            frag_t bf = *(const frag_t*)(W2bf + (c * 16 + n16) * 128 + ks * 32 + quad * 8);
            #pragma unroll
            for (int t = 0; t < 2; ++t)
                acc2[t][c] = __builtin_amdgcn_mfma_f32_16x16x32_bf16(a[t], bf, acc2[t][c], 0, 0, 0);
        }
    }

    // ---------- Epilogue: LDS bounce -> fully-coalesced float4 stores ----------
    // Reuse Hw bytes as fp32 [32 x 68] (stride 68 floats: 16B-aligned rows,
    // worst 4-way bank aliasing on the b128 readback - negligible over 8 reads).
    float* Fw = (float*)Hw;
    __threadfence_block();   // order Fw writes after Hw bf16 reads (type-aliased LDS)
    #pragma unroll
    for (int c = 0; c < 4; ++c) {
        float bv = b2[c * 16 + n16];
        #pragma unroll
        for (int t = 0; t < 2; ++t) {
            #pragma unroll
            for (int r = 0; r < 4; ++r) {
                int row = t * 16 + quad * 4 + r;
                Fw[row * 68 + c * 16 + n16] = acc2[t][c][r] + bv;
            }
        }
    }
    __threadfence_block();   // order readback after Fw writes

    // Wave's output = one contiguous 8 KB block: 8 passes x (64 lanes x 16 B).
    // Every 128B line is fully written by a single instruction -> no partial-line
    // eviction window, WRITE_SIZE stays at the 133.7 MB ideal.
    float* ob = out + ((long)b * 65280 + e0) * 64;
    #pragma unroll
    for (int p = 0; p < 8; ++p) {
        int row = p * 4 + quad;
        f32x4 v = *(const f32x4*)&Fw[row * 68 + n16 * 4];
        *(f32x4*)&ob[p * 256 + lane * 4] = v;
    }
}

extern "C" void kernel_launch(void* const* d_in, const int* in_sizes, int n_in,
                              void* d_out, int out_size, void* d_ws, size_t ws_size,
                              hipStream_t stream) {
    const float* x  = (const float*)d_in[0];
    // d_in[1] = rel_rec, d_in[2] = rel_send: one-hot incidence, replaced by index math
    const float* W1 = (const float*)d_in[3];
    const float* b1 = (const float*)d_in[4];
    const float* W2 = (const float*)d_in[5];
    const float* b2 = (const float*)d_in[6];
    unsigned short* ws = (unsigned short*)d_ws;
    float* out = (float*)d_out;

    cvt_bf16<<<64, 256, 0, stream>>>(x, W1, W2, ws);
    // 510 edge-blocks of 128 edges x 8 batches (batch = bx&7 -> XCD-pinned)
    nri_mlp<<<4080, 256, 0, stream>>>(ws, b1, b2, out);
}

// Round 4
// 260.672 us; speedup vs baseline: 1.2345x; 1.1782x over previous
//
#include <hip/hip_runtime.h>
#include <hip/hip_bf16.h>

// NRI edge-MLP encoder: out[b,e,:] = relu(concat(x[b,send(e)], x[b,recv(e)]) @ W1^T + b1) @ W2^T + b2
// B=8, N=256, E=65280, n_in=64, n_hid=128, n_out=64.
// edge e: recv = e/255, k = e%255, send = k + (k >= recv)

using frag_t  = __attribute__((ext_vector_type(8))) short;          // 8 bf16 = 4 VGPRs
using f32x4   = __attribute__((ext_vector_type(4))) float;
using ushort8 = __attribute__((ext_vector_type(8))) unsigned short;

#define X_ELEMS  (8 * 256 * 64)   // 131072
#define W1_ELEMS (128 * 128)
#define W2_ELEMS (64 * 128)
#define W1_OFF   X_ELEMS
#define W2_OFF   (X_ELEMS + W1_ELEMS)

typedef __attribute__((address_space(3))) unsigned short       lds_us;
typedef __attribute__((address_space(1))) const unsigned short glb_us;

__device__ inline unsigned short f2bf(float f) {
    union { float f; unsigned u; } v; v.f = f;
    unsigned r = v.u + 0x7fffu + ((v.u >> 16) & 1u);   // RTNE
    return (unsigned short)(r >> 16);
}

__device__ inline void cvt8(const float* __restrict__ s, unsigned short* __restrict__ d) {
    f32x4 a = *(const f32x4*)s;
    f32x4 b = *(const f32x4*)(s + 4);
    ushort8 o;
    o[0] = f2bf(a[0]); o[1] = f2bf(a[1]); o[2] = f2bf(a[2]); o[3] = f2bf(a[3]);
    o[4] = f2bf(b[0]); o[5] = f2bf(b[1]); o[6] = f2bf(b[2]); o[7] = f2bf(b[3]);
    *(ushort8*)d = o;
}

__global__ __launch_bounds__(256) void cvt_bf16(const float* __restrict__ x,
                                                const float* __restrict__ W1,
                                                const float* __restrict__ W2,
                                                unsigned short* __restrict__ ws) {
    int g = blockIdx.x * 256 + threadIdx.x;           // 64 blocks -> 16384 threads
    cvt8(x + g * 8, ws + g * 8);                      // covers X_ELEMS exactly
    if (g < W1_ELEMS / 8) cvt8(W1 + g * 8, ws + W1_OFF + g * 8);
    if (g < W2_ELEMS / 8) cvt8(W2 + g * 8, ws + W2_OFF + g * 8);
}

// grid 2040 = 8 batches x 255 blocks x 256 edges. Wave owns 64 edges, no barriers.
// LDS: per-wave 16 KB A/H buffer, row-major 128 elem rows, 16B chunks XOR-swizzled
// (slot = chunk ^ (row&7)) so global_load_lds's no-padding constraint coexists with
// conflict-free ds_read_b128 fragments. W1/W2 fragments live in registers, reused
// over 4 tiles. Layer2 computes out^T = W2 @ H^T -> C-layout rows = 4 consecutive
// out-features -> direct float4 stores.
__global__ __launch_bounds__(256, 2) void nri_mlp(const unsigned short* __restrict__ ws,
                                                  const float* __restrict__ b1,
                                                  const float* __restrict__ b2,
                                                  float* __restrict__ out) {
    const unsigned short* xbf  = ws;
    const unsigned short* W1bf = ws + W1_OFF;
    const unsigned short* W2bf = ws + W2_OFF;

    __shared__ unsigned short Sh[4][64 * 128];   // 64 KB: 4 waves x (64 edges x 128)

    const int tid  = threadIdx.x;
    const int wave = tid >> 6;
    const int lane = tid & 63;
    const int quad = lane >> 4;
    const int n16  = lane & 15;

    const int bx = blockIdx.x;
    const int b  = bx / 255;
    const int eb = (bx - b * 255) * 256;
    const int e0 = eb + wave * 64;               // this wave's 64 edges

    const unsigned short* xb = xbf + b * (256 * 64);
    unsigned short* Aw = &Sh[wave][0];

    // ---- stage A: 16 async 1KB instructions; lane ℓ -> row i*4+ℓ/16, slot ℓ%16 ----
    {
        const int r4   = lane >> 4;      // 0..3
        const int slot = lane & 15;
        #pragma unroll
        for (int i = 0; i < 16; ++i) {
            int rr   = i * 4 + r4;                       // local edge row 0..63
            int e    = e0 + rr;
            int recv = e / 255;
            int kk   = e - recv * 255;
            int send = kk + (kk >= recv ? 1 : 0);
            int c    = slot ^ (rr & 7);                  // data chunk stored at this slot
            int node = (c < 8) ? send : recv;
            const unsigned short* src = xb + node * 64 + (c & 7) * 8;
            __builtin_amdgcn_global_load_lds((glb_us*)src, (lds_us*)(Aw + i * 512), 16, 0, 0);
        }
    }

    // ---- W1 fragments -> registers (B-operand: lane n16 = W1 row, k-run) ----
    frag_t w1f[4][8];
    #pragma unroll
    for (int ks = 0; ks < 4; ++ks)
        #pragma unroll
        for (int c = 0; c < 8; ++c)
            w1f[ks][c] = *(const frag_t*)(W1bf + (c * 16 + n16) * 128 + ks * 32 + quad * 8);

    float b1v[8];
    #pragma unroll
    for (int c = 0; c < 8; ++c) b1v[c] = b1[c * 16 + n16];

    __builtin_amdgcn_s_waitcnt(0);   // drain staging (global_load_lds) before ds_read

    // ---- phase 1: H = relu(A @ W1^T + b1), tile-by-tile, H overwrites A rows ----
    #pragma unroll
    for (int t = 0; t < 4; ++t) {
        frag_t af[4];
        #pragma unroll
        for (int ks = 0; ks < 4; ++ks) {
            int r    = t * 16 + n16;
            int slot = (ks * 4 + quad) ^ (r & 7);
            af[ks] = *(const frag_t*)&Aw[r * 128 + slot * 8];
        }
        f32x4 acc[8];
        #pragma unroll
        for (int c = 0; c < 8; ++c) acc[c] = (f32x4){0.f, 0.f, 0.f, 0.f};
        #pragma unroll
        for (int ks = 0; ks < 4; ++ks)
            #pragma unroll
            for (int c = 0; c < 8; ++c)
                acc[c] = __builtin_amdgcn_mfma_f32_16x16x32_bf16(af[ks], w1f[ks][c], acc[c], 0, 0, 0);

        // C-layout: col = n16 (hid feat c*16+n16), row = quad*4+r_i (edge row)
        #pragma unroll
        for (int c = 0; c < 8; ++c) {
            float bv = b1v[c];
            #pragma unroll
            for (int ri = 0; ri < 4; ++ri) {
                float v = acc[c][ri] + bv;
                v = v > 0.f ? v : 0.f;
                int row  = t * 16 + quad * 4 + ri;
                int k    = c * 16 + n16;
                int slot = (k >> 3) ^ (row & 7);
                Aw[row * 128 + slot * 8 + (n16 & 7)] = f2bf(v);
            }
        }
    }

    // ---- phase 2: out^T = W2 @ H^T. A-operand = W2 rows, B-operand = H rows ----
    frag_t w2f[4][4];
    #pragma unroll
    for (int ks = 0; ks < 4; ++ks)
        #pragma unroll
        for (int c2 = 0; c2 < 4; ++c2)
            w2f[ks][c2] = *(const frag_t*)(W2bf + (c2 * 16 + n16) * 128 + ks * 32 + quad * 8);

    float b2v[4][4];
    #pragma unroll
    for (int c2 = 0; c2 < 4; ++c2)
        #pragma unroll
        for (int ri = 0; ri < 4; ++ri)
            b2v[c2][ri] = b2[c2 * 16 + quad * 4 + ri];

    #pragma unroll
    for (int t = 0; t < 4; ++t) {
        frag_t hf[4];
        #pragma unroll
        for (int ks = 0; ks < 4; ++ks) {
            int r    = t * 16 + n16;
            int slot = (ks * 4 + quad) ^ (r & 7);
            hf[ks] = *(const frag_t*)&Aw[r * 128 + slot * 8];
        }
        f32x4 acc2[4];
        #pragma unroll
        for (int c2 = 0; c2 < 4; ++c2) acc2[c2] = (f32x4){0.f, 0.f, 0.f, 0.f};
        #pragma unroll
        for (int ks = 0; ks < 4; ++ks)
            #pragma unroll
            for (int c2 = 0; c2 < 4; ++c2)
                acc2[c2] = __builtin_amdgcn_mfma_f32_16x16x32_bf16(w2f[ks][c2], hf[ks], acc2[c2], 0, 0, 0);

        // C-layout: col = n16 = edge, row = quad*4+reg = out-feature -> float4 store
        float* ob = out + ((long)b * 65280 + e0 + t * 16 + n16) * 64;
        #pragma unroll
        for (int c2 = 0; c2 < 4; ++c2) {
            f32x4 v;
            #pragma unroll
            for (int ri = 0; ri < 4; ++ri) v[ri] = acc2[c2][ri] + b2v[c2][ri];
            *(f32x4*)&ob[c2 * 16 + quad * 4] = v;
        }
    }
}

extern "C" void kernel_launch(void* const* d_in, const int* in_sizes, int n_in,
                              void* d_out, int out_size, void* d_ws, size_t ws_size,
                              hipStream_t stream) {
    const float* x  = (const float*)d_in[0];
    // d_in[1] = rel_rec, d_in[2] = rel_send: one-hot incidence, replaced by index math
    const float* W1 = (const float*)d_in[3];
    const float* b1 = (const float*)d_in[4];
    const float* W2 = (const float*)d_in[5];
    const float* b2 = (const float*)d_in[6];
    unsigned short* ws = (unsigned short*)d_ws;
    float* out = (float*)d_out;

    cvt_bf16<<<64, 256, 0, stream>>>(x, W1, W2, ws);
    nri_mlp<<<2040, 256, 0, stream>>>(ws, b1, b2, out);
}